// Round 9
// baseline (597.576 us; speedup 1.0000x reference)
//
#include <hip/hip_runtime.h>
#include <hip/hip_bf16.h>
#include <math.h>

#define B_ROWS 32768

typedef __attribute__((ext_vector_type(8)))  short        s8v;
typedef __attribute__((ext_vector_type(4)))  float        f4v;
typedef __attribute__((ext_vector_type(2)))  unsigned int u2v;
typedef __attribute__((ext_vector_type(4)))  unsigned int u4v;

__device__ __forceinline__ short f2bf(float f){            // f32 -> bf16 RNE (cvtw helper)
  unsigned u = __builtin_bit_cast(unsigned, f);
  u = (u + 0x7fffu + ((u >> 16) & 1u)) >> 16;
  return (short)u;
}
// packed pair convert (RNE, low = a, high = b) — no inline asm (rounds 2/7 NaN'd with it)
__device__ __forceinline__ unsigned cpk(float a, float b){
  __hip_bfloat16_raw lo = (__hip_bfloat16_raw)__float2bfloat16(a);
  __hip_bfloat16_raw hi = (__hip_bfloat16_raw)__float2bfloat16(b);
  return (unsigned)lo.x | ((unsigned)hi.x << 16);
}
__device__ __forceinline__ float bf_lo(unsigned u){ return __builtin_bit_cast(float, u << 16); }
__device__ __forceinline__ float bf_hi(unsigned u){ return __builtin_bit_cast(float, u & 0xffff0000u); }

#define MFMA16(A,B,C) __builtin_amdgcn_mfma_f32_16x16x32_bf16((A),(B),(C),0,0,0)

// ---------------- LDS layout (bytes) — 78.9KB/WG => 2 WGs/CU ----------------
#define OXFT 0          // f32 [64 dims][68] x-state transposed (pad 4, 16B-aligned rows)
#define XFT_S 68
#define OHB   17408     // bf16 [64 batch][136] hidden chunk (per-wave disjoint col regions)
#define HB_S  136
#define OW1   34816     // bf16 [128][168] W1 chunk SINGLE buffer (43008B)
#define W1_S  168
#define OSL   OW1       // 4 slots x bf16[64][68] (8704B) alias W1 (dead at slot time)
#define SL_S  68
#define SLOT_B 8704
#define OLJ   77824     // f32[64]
#define OPERM 78080     // int[64]
#define OELS  78336     // f32[64]
#define OBIV  78592     // f32[64]
#define OSLS  78848     // f32 scalar
#define SM_SZ 78864

// ws (bf16 weights) element offsets
#define O_S1W1 0
#define O_S1W2 983040
#define O_S2W1 1376256
#define O_S2W2 2359296
#define W_TOTAL 2752512

__global__ void cvtw(const float* __restrict__ s1w1, const float* __restrict__ s1w2,
                     const float* __restrict__ s2w1, const float* __restrict__ s2w2,
                     unsigned short* __restrict__ dst)
{
  long t = (long)blockIdx.x * blockDim.x + threadIdx.x;
  if (t >= W_TOTAL) return;
  float v;
  if      (t < O_S1W2) v = s1w1[t];
  else if (t < O_S2W1) v = s1w2[t - O_S1W2];
  else if (t < O_S2W2) v = s2w1[t - O_S2W1];
  else                 v = s2w2[t - O_S2W2];
  dst[t] = (unsigned short)f2bf(v);
}

template<int USEBF>
__device__ __forceinline__ s8v ldw(const unsigned short* wb, const float* wf, int off){
  if (USEBF){
    return *(const s8v*)(wb + off);
  } else {
    f4v a = *(const f4v*)(wf + off);
    f4v b = *(const f4v*)(wf + off + 4);
    u4v u = {cpk(a[0],a[1]), cpk(a[2],a[3]), cpk(b[0],b[1]), cpk(b[2],b[3])};
    return __builtin_bit_cast(s8v, u);
  }
}

struct MP { const unsigned short* w1b; const float* w1f;
            const unsigned short* w2b; const float* w2f;
            const float* b1; const float* b2; };

__device__ __forceinline__ MP getmp(int m, const unsigned short* wbf,
    const float* s1W1f, const float* s1W2f, const float* s2W1f, const float* s2W2f,
    const float* s1b1, const float* s1b2, const float* s2b1, const float* s2b2)
{
  int blk = m >> 1;
  MP r;
  if (m & 1){
    r.w1b = wbf + O_S1W1 + (size_t)blk*81920; r.w1f = s1W1f + (size_t)blk*81920;
    r.w2b = wbf + O_S1W2 + (size_t)blk*32768; r.w2f = s1W2f + (size_t)blk*32768;
    r.b1 = s1b1 + blk*512; r.b2 = s1b2 + blk*64;
  } else {
    r.w1b = wbf + O_S2W1 + (size_t)blk*81920; r.w1f = s2W1f + (size_t)blk*81920;
    r.w2b = wbf + O_S2W2 + (size_t)blk*32768; r.w2f = s2W2f + (size_t)blk*32768;
    r.b1 = s2b1 + blk*512; r.b2 = s2b2 + blk*64;
  }
  return r;
}

// issue coalesced global loads of one 128-hidden W1 chunk (256 threads)
template<int USEBF>
__device__ __forceinline__ void issue_w1(const MP& p, int cchunk, int tid,
                                         u4v wt[10], f4v wtf[20])
{
  if (USEBF){
    const unsigned short* s = p.w1b + cchunk*20480;
    #pragma unroll
    for (int k = 0; k < 10; ++k) wt[k] = *(const u4v*)(s + (size_t)(k*256+tid)*8);
  } else {
    const float* s = p.w1f + cchunk*20480;
    #pragma unroll
    for (int k = 0; k < 20; ++k) wtf[k] = *(const f4v*)(s + (size_t)(k*256+tid)*4);
  }
}

// commit staged W1 registers into padded LDS buffer (row/col precomputed)
template<int USEBF>
__device__ __forceinline__ void write_w1(char* sm,
                                         const u4v wt[10], const f4v wtf[20],
                                         const int* wr, const int* wc)
{
  short* W1n = (short*)(sm + OW1);
  if (USEBF){
    #pragma unroll
    for (int k = 0; k < 10; ++k)
      *(u4v*)(W1n + wr[k]*W1_S + wc[k]*8) = wt[k];
  } else {
    #pragma unroll
    for (int k = 0; k < 20; ++k){
      f4v v = wtf[k];
      *(u2v*)(W1n + wr[k]*W1_S + wc[k]*4) = (u2v){cpk(v[0],v[1]), cpk(v[2],v[3])};
    }
  }
}

template<int USEBF>
__global__ __launch_bounds__(256, 2) void cinn_t(
    const float* __restrict__ q, const float* __restrict__ Hg,
    const int* __restrict__ perms,
    const float* __restrict__ ls_g, const float* __restrict__ bi_g,
    const float* __restrict__ s1b1, const float* __restrict__ s1b2,
    const float* __restrict__ s2b1, const float* __restrict__ s2b2,
    const unsigned short* __restrict__ wbf,
    const float* __restrict__ s1W1f, const float* __restrict__ s1W2f,
    const float* __restrict__ s2W1f, const float* __restrict__ s2W2f,
    float* __restrict__ outz, float* __restrict__ outlj)
{
  __shared__ __align__(16) char sm[SM_SZ];
  const int tid = threadIdx.x;
  const int rowbase = blockIdx.x * 64;
  const int lane = tid & 63;
  const int hw = tid >> 6;                 // wave id 0..3 = hidden-row group / k-split group
  const int l15 = lane & 15, lq = lane >> 4;

  float* XFT = (float*)(sm + OXFT);
  short* HB  = (short*)(sm + OHB);
  float* LOGJ= (float*)(sm + OLJ);
  int*   PERM= (int*)(sm + OPERM);
  float* ELS = (float*)(sm + OELS);
  float* BIV = (float*)(sm + OBIV);
  float* SLSp= (float*)(sm + OSLS);

  // staging row/col precompute (runtime div once)
  int wr[20], wc[20];
  if (USEBF){
    #pragma unroll
    for (int k = 0; k < 10; ++k){ int i = k*256 + tid; wr[k] = i/20; wc[k] = i - wr[k]*20; }
  } else {
    #pragma unroll
    for (int k = 0; k < 20; ++k){ int i = k*256 + tid; wr[k] = i/40; wc[k] = i - wr[k]*40; }
  }

  // init XFT from q (coalesced read, strided LDS write, once)
  {
    int b = tid >> 2, j = tid & 3;
    const float* src = q + (size_t)(rowbase + b)*64 + j*16;
    #pragma unroll
    for (int i = 0; i < 4; ++i){
      f4v v = *(const f4v*)(src + 4*i);
      #pragma unroll
      for (int jj = 0; jj < 4; ++jj)
        XFT[(j*16 + 4*i + jj)*XFT_S + b] = v[jj];
    }
  }
  if (tid < 64) LOGJ[tid] = 0.f;
  if (tid == 0) *SLSp = 0.f;
  __syncthreads();
  if (tid < 64){
    float p = 0.f;
    #pragma unroll
    for (int k = 0; k < 12; ++k) p += ls_g[k*64 + tid];
    atomicAdd(SLSp, p);
  }

  // H-part B-fragments (all 64 batches, 4 nt tiles): loaded ONCE, register-resident
  s8v hfr[4][4];
  #pragma unroll
  for (int nt = 0; nt < 4; ++nt){
    int b = rowbase + nt*16 + l15;
    #pragma unroll
    for (int kkh = 0; kkh < 4; ++kkh){
      const float* hp = Hg + (size_t)b*128 + kkh*32 + lq*8;
      f4v a = *(const f4v*)hp;
      f4v c = *(const f4v*)(hp + 4);
      u4v u = {cpk(a[0],a[1]), cpk(a[2],a[3]), cpk(c[0],c[1]), cpk(c[2],c[3])};
      hfr[nt][kkh] = __builtin_bit_cast(s8v, u);
    }
  }

  // prologue: stage MLP0 chunk0 into the single W1 buffer
  u4v wt[10]; f4v wtf[20];
  {
    MP p0 = getmp(0, wbf, s1W1f, s1W2f, s2W1f, s2W2f, s1b1, s1b2, s2b1, s2b2);
    issue_w1<USEBF>(p0, 0, tid, wt, wtf);
    write_w1<USEBF>(sm, wt, wtf, wr, wc);
  }
  __syncthreads();

  for (int m = 0; m < 24; ++m){
    const int bp = m & 1;
    MP cur = getmp(m, wbf, s1W1f, s1W2f, s2W1f, s2W2f, s1b1, s1b2, s2b1, s2b2);
    MP nxt = getmp(m < 23 ? m + 1 : 23, wbf, s1W1f, s1W2f, s2W1f, s2W2f, s1b1, s1b2, s2b1, s2b2);

    if (!bp){
      int blk = m >> 1;
      if (tid < 64){
        PERM[tid] = perms[blk*64 + tid];
        ELS[tid]  = __expf(ls_g[blk*64 + tid]);
        BIV[tid]  = bi_g[blk*64 + tid];
      }
      __syncthreads();
      // permute + affine on XFT (read-all / barrier / write-all)
      {
        int d = lane, bg = hw;          // d: dim, bg: 16-batch group
        int pd = PERM[d];
        f4v v[4];
        #pragma unroll
        for (int i = 0; i < 4; ++i)
          v[i] = *(const f4v*)(XFT + pd*XFT_S + bg*16 + 4*i);
        __syncthreads();
        float e = ELS[d], bi = BIV[d];
        #pragma unroll
        for (int i = 0; i < 4; ++i){
          #pragma unroll
          for (int jj = 0; jj < 4; ++jj) v[i][jj] = fmaf(v[i][jj], e, bi);
          *(f4v*)(XFT + d*XFT_S + bg*16 + 4*i) = v[i];
        }
      }
      __syncthreads();
    }

    // x-part B-frags from XFT (dims xbase..+31)
    const int xbase = bp ? 0 : 32;
    s8v xk[4];
    #pragma unroll
    for (int nt = 0; nt < 4; ++nt){
      int b = nt*16 + l15;
      const float* xp = XFT + (xbase + lq*8)*XFT_S + b;
      u4v u;
      #pragma unroll
      for (int p = 0; p < 4; ++p)
        u[p] = cpk(xp[(2*p)*XFT_S], xp[(2*p+1)*XFT_S]);
      xk[nt] = __builtin_bit_cast(s8v, u);
    }

    // b2 (added by hw==0 wave at slot-write time)
    f4v b2v[4];
    if (hw == 0){
      #pragma unroll
      for (int ot = 0; ot < 4; ++ot)
        b2v[ot] = *(const f4v*)(cur.b2 + ot*16 + lq*4);
    }

    f4v racc[4][4];
    #pragma unroll
    for (int ot = 0; ot < 4; ++ot)
      #pragma unroll
      for (int nt = 0; nt < 4; ++nt)
        racc[ot][nt] = (f4v){0.f,0.f,0.f,0.f};

    #pragma unroll
    for (int c = 0; c < 4; ++c){
      // issue next W1 chunk loads (regs; committed at the next safe barrier)
      const MP& pn = (c < 3) ? cur : nxt;
      const int cn = (c < 3) ? c + 1 : 0;
      if (!(m == 23 && c == 3)) issue_w1<USEBF>(pn, cn, tid, wt, wtf);
      // W2 A-frags for this chunk (global/L2; consumed after GEMM1 -> latency hidden)
      s8v w2c[4];
      #pragma unroll
      for (int ot = 0; ot < 4; ++ot)
        w2c[ot] = ldw<USEBF>(cur.w2b, cur.w2f, (ot*16 + l15)*512 + c*128 + hw*32 + lq*8);
      // b1 for this chunk (consumed after GEMM1)
      f4v b1v0 = *(const f4v*)(cur.b1 + c*128 + hw*32 + lq*4);
      f4v b1v1 = *(const f4v*)(cur.b1 + c*128 + hw*32 + 16 + lq*4);

      // ---- GEMM1 chunk c: hidden rows c*128 + hw*32 + {0,16}
      const short* W1c = (const short*)(sm + OW1);
      f4v acc[2][4];
      #pragma unroll
      for (int mt = 0; mt < 2; ++mt)
        #pragma unroll
        for (int nt = 0; nt < 4; ++nt) acc[mt][nt] = (f4v){0.f,0.f,0.f,0.f};
      #pragma unroll
      for (int kk = 0; kk < 5; ++kk){
        s8v a0 = *(const s8v*)(W1c + (hw*32 +  0 + l15)*W1_S + kk*32 + lq*8);
        s8v a1 = *(const s8v*)(W1c + (hw*32 + 16 + l15)*W1_S + kk*32 + lq*8);
        #pragma unroll
        for (int nt = 0; nt < 4; ++nt){
          s8v bb = (kk == 0) ? xk[nt] : hfr[nt][kk-1];
          acc[0][nt] = MFMA16(a0, bb, acc[0][nt]);
          acc[1][nt] = MFMA16(a1, bb, acc[1][nt]);
        }
      }
      // bias + relu + pack -> own HB column region (in-wave, no barrier)
      #pragma unroll
      for (int mt = 0; mt < 2; ++mt){
        f4v bv = mt ? b1v1 : b1v0;
        #pragma unroll
        for (int nt = 0; nt < 4; ++nt){
          float h0 = fmaxf(acc[mt][nt][0] + bv[0], 0.f);
          float h1 = fmaxf(acc[mt][nt][1] + bv[1], 0.f);
          float h2 = fmaxf(acc[mt][nt][2] + bv[2], 0.f);
          float h3 = fmaxf(acc[mt][nt][3] + bv[3], 0.f);
          *(u2v*)(HB + (nt*16 + l15)*HB_S + hw*32 + mt*16 + lq*4) = (u2v){cpk(h0,h1), cpk(h2,h3)};
        }
      }
      // ---- GEMM2 k-slice: read back OWN rows (in-wave)
      #pragma unroll
      for (int nt = 0; nt < 4; ++nt){
        s8v bb = *(const s8v*)(HB + (nt*16 + l15)*HB_S + hw*32 + lq*8);
        #pragma unroll
        for (int ot = 0; ot < 4; ++ot)
          racc[ot][nt] = MFMA16(w2c[ot], bb, racc[ot][nt]);
      }
      __syncthreads();                     // A: all waves done reading W1[c]
      if (c < 3){
        write_w1<USEBF>(sm, wt, wtf, wr, wc);
        __syncthreads();                   // B: W1[c+1] visible
      }
    }

    // ---- slots (alias the now-dead W1 buffer): bf16 k-partials, +b2 on hw0
    {
      short* SL = (short*)(sm + OSL + hw*SLOT_B);
      #pragma unroll
      for (int ot = 0; ot < 4; ++ot)
        #pragma unroll
        for (int nt = 0; nt < 4; ++nt){
          float r0 = racc[ot][nt][0], r1 = racc[ot][nt][1];
          float r2 = racc[ot][nt][2], r3 = racc[ot][nt][3];
          if (hw == 0){ r0 += b2v[ot][0]; r1 += b2v[ot][1]; r2 += b2v[ot][2]; r3 += b2v[ot][3]; }
          *(u2v*)(SL + (nt*16 + l15)*SL_S + ot*16 + lq*4) = (u2v){cpk(r0,r1), cpk(r2,r3)};
        }
    }
    __syncthreads();

    // ---- coupling: sum 4 slots, le = 0.636*atan(rL); y = exp(le)*x_half + rR
    {
      int b = tid & 63, og = tid >> 6;
      float le[8] = {0,0,0,0,0,0,0,0}, ra[8] = {0,0,0,0,0,0,0,0};
      #pragma unroll
      for (int ms = 0; ms < 4; ++ms){
        const short* SL = (const short*)(sm + OSL + ms*SLOT_B);
        u2v L0 = *(const u2v*)(SL + b*SL_S + og*8);
        u2v L1 = *(const u2v*)(SL + b*SL_S + og*8 + 4);
        u2v R0 = *(const u2v*)(SL + b*SL_S + 32 + og*8);
        u2v R1 = *(const u2v*)(SL + b*SL_S + 32 + og*8 + 4);
        le[0]+=bf_lo(L0[0]); le[1]+=bf_hi(L0[0]); le[2]+=bf_lo(L0[1]); le[3]+=bf_hi(L0[1]);
        le[4]+=bf_lo(L1[0]); le[5]+=bf_hi(L1[0]); le[6]+=bf_lo(L1[1]); le[7]+=bf_hi(L1[1]);
        ra[0]+=bf_lo(R0[0]); ra[1]+=bf_hi(R0[0]); ra[2]+=bf_lo(R0[1]); ra[3]+=bf_hi(R0[1]);
        ra[4]+=bf_lo(R1[0]); ra[5]+=bf_hi(R1[0]); ra[6]+=bf_lo(R1[1]); ra[7]+=bf_hi(R1[1]);
      }
      float part = 0.f;
      #pragma unroll
      for (int j = 0; j < 8; ++j){
        float l = 0.636f * atanf(le[j]);
        int d = bp*32 + og*8 + j;
        float y = __expf(l) * XFT[d*XFT_S + b] + ra[j];
        XFT[d*XFT_S + b] = y;
        part += l;
      }
      atomicAdd(&LOGJ[b], part);
    }
    __syncthreads();

    // commit next MLP's chunk0 (slots are dead after the coupling barrier)
    if (m < 23){
      write_w1<USEBF>(sm, wt, wtf, wr, wc);
      __syncthreads();
    }
  }

  // output: transpose back, coalesced global writes
  {
    int b = tid >> 2, j = tid & 3;
    float* dst = outz + (size_t)(rowbase + b)*64 + j*16;
    #pragma unroll
    for (int i = 0; i < 4; ++i){
      f4v w;
      #pragma unroll
      for (int jj = 0; jj < 4; ++jj)
        w[jj] = XFT[(j*16 + 4*i + jj)*XFT_S + b];
      *(f4v*)(dst + 4*i) = w;
    }
  }
  if (tid < 64) outlj[rowbase + tid] = LOGJ[tid] + *SLSp;
}

extern "C" void kernel_launch(void* const* d_in, const int* in_sizes, int n_in,
                              void* d_out, int out_size, void* d_ws, size_t ws_size,
                              hipStream_t stream)
{
  const float* q    = (const float*)d_in[0];
  const float* Hg   = (const float*)d_in[1];
  const int*   perms= (const int*)  d_in[2];
  const float* ls   = (const float*)d_in[3];
  const float* bi   = (const float*)d_in[4];
  const float* s1W1 = (const float*)d_in[5];
  const float* s1b1 = (const float*)d_in[6];
  const float* s1W2 = (const float*)d_in[7];
  const float* s1b2 = (const float*)d_in[8];
  const float* s2W1 = (const float*)d_in[9];
  const float* s2b1 = (const float*)d_in[10];
  const float* s2W2 = (const float*)d_in[11];
  const float* s2b2 = (const float*)d_in[12];
  float* outz  = (float*)d_out;
  float* outlj = outz + (size_t)B_ROWS * 64;

  int usebf = (ws_size >= (size_t)W_TOTAL * 2) ? 1 : 0;
  unsigned short* wbf = (unsigned short*)d_ws;
  if (usebf){
    cvtw<<<2688, 1024, 0, stream>>>(s1W1, s1W2, s2W1, s2W2, wbf);
    cinn_t<1><<<512, 256, 0, stream>>>(q, Hg, perms, ls, bi,
                                       s1b1, s1b2, s2b1, s2b2,
                                       wbf, s1W1, s1W2, s2W1, s2W2,
                                       outz, outlj);
  } else {
    cinn_t<0><<<512, 256, 0, stream>>>(q, Hg, perms, ls, bi,
                                       s1b1, s1b2, s2b1, s2b2,
                                       wbf, s1W1, s1W2, s2W1, s2W2,
                                       outz, outlj);
  }
}

// Round 10
// 262.278 us; speedup vs baseline: 2.2784x; 2.2784x over previous
//
#include <hip/hip_runtime.h>
#include <hip/hip_bf16.h>
#include <math.h>

#define B_ROWS 32768

typedef __attribute__((ext_vector_type(8)))  short        s8v;
typedef __attribute__((ext_vector_type(4)))  float        f4v;
typedef __attribute__((ext_vector_type(2)))  unsigned int u2v;
typedef __attribute__((ext_vector_type(4)))  unsigned int u4v;

__device__ __forceinline__ short f2bf(float f){            // f32 -> bf16 RNE
  unsigned u = __builtin_bit_cast(unsigned, f);
  u = (u + 0x7fffu + ((u >> 16) & 1u)) >> 16;
  return (short)u;
}
// packed pair convert (RNE, low = a, high = b) — builtin path (asm variant NaN'd in r2/r7)
__device__ __forceinline__ unsigned cpk(float a, float b){
  __hip_bfloat16_raw lo = (__hip_bfloat16_raw)__float2bfloat16(a);
  __hip_bfloat16_raw hi = (__hip_bfloat16_raw)__float2bfloat16(b);
  return (unsigned)lo.x | ((unsigned)hi.x << 16);
}
__device__ __forceinline__ float bf_lo(unsigned u){ return __builtin_bit_cast(float, u << 16); }
__device__ __forceinline__ float bf_hi(unsigned u){ return __builtin_bit_cast(float, u & 0xffff0000u); }

#define MFMA16(A,B,C) __builtin_amdgcn_mfma_f32_16x16x32_bf16((A),(B),(C),0,0,0)

// direct global->LDS DMA, 16B per lane; lds base must be wave-uniform
typedef __attribute__((address_space(1))) const unsigned int gu32;
typedef __attribute__((address_space(3))) unsigned int lu32;
__device__ __forceinline__ void gl_lds16(const unsigned short* g, char* l){
  __builtin_amdgcn_global_load_lds((gu32*)(const void*)g, (lu32*)(void*)l, 16, 0, 0);
}

// ---------------- LDS layout (bytes) ----------------
#define OXFT 0          // f32 [64 dims][132] x-state transposed
#define XFT_S 132
#define OHB   33792     // bf16 [128 batch][136] hidden chunk (per-wave disjoint cols)
#define HB_S  136
#define OW1   68608     // 2 x 40960B W1 chunk double buffer, fragment-linear (40 tiles x 1KB)
#define W1BUF 40960
#define OLJ   150528    // f32[128]
#define OPERM 151040    // int[64]
#define OELS  151296    // f32[64]
#define OBIV  151552    // f32[64]
#define OSLS  151808    // f32 scalar
#define SM_SZ 151812

// reduce slots: bf16 [128][68] each (17408B). Slots 0,1 alias W1 buf1; slots 2,3 alias HB.
// Liveness: written after post-chunk3 barrier (buf1 + HB dead: chunk3 read buf1, next-MLP
// chunk0 prefetch goes to buf0); consumed in coupling before next MLP's c=0 DMA (-> buf1).
#define SL_S 68
#define SLOT_B 17408
#define OSLB1 (OW1 + W1BUF)

// ws (bf16, fragment-linear): W1 sec [24 mlps][4 chunks][40 tiles][512], W2 sec [24][64 tiles][512]
#define WF_W2 1966080
#define W_TOTAL 2752512

// -------- one-time f32 -> bf16 fragment-linear rearrangement --------
// W1 tile (m,c,rg,kk): lane l=(l15,lq) elems e0..7 = W1[h=c*128+rg*16+l15][k=kk*32+lq*8+e]
// W2 tile (m,c,hw,ot): lane l elems = W2[o=ot*16+l15][h=c*128+hw*32+lq*8+e]
__global__ void cvtw_frag(const float* __restrict__ s1w1, const float* __restrict__ s1w2,
                          const float* __restrict__ s2w1, const float* __restrict__ s2w2,
                          unsigned short* __restrict__ dst)
{
  long t = (long)blockIdx.x * blockDim.x + threadIdx.x;
  if (t >= W_TOTAL) return;
  float v;
  if (t < WF_W2){
    int m = (int)(t / 81920); int r = (int)(t - (long)m*81920);
    int c = r / 20480;  int r2 = r - c*20480;
    int tile = r2 >> 9; int r3 = r2 & 511;
    int lane = r3 >> 3; int e = r3 & 7;
    int rg = tile / 5,  kk = tile - rg*5;
    int l15 = lane & 15, lq = lane >> 4;
    int h  = c*128 + rg*16 + l15;
    int ki = kk*32 + lq*8 + e;
    const float* src = (m & 1) ? s1w1 : s2w1;
    v = src[(size_t)(m >> 1)*81920 + h*160 + ki];
  } else {
    long u = t - WF_W2;
    int m = (int)(u / 32768); int r = (int)(u - (long)m*32768);
    int g = r >> 9; int r3 = r & 511;
    int lane = r3 >> 3; int e = r3 & 7;
    int c = g >> 4, hw = (g >> 2) & 3, ot = g & 3;
    int l15 = lane & 15, lq = lane >> 4;
    int o = ot*16 + l15;
    int h = c*128 + hw*32 + lq*8 + e;
    const float* src = (m & 1) ? s1w2 : s2w2;
    v = src[(size_t)(m >> 1)*32768 + o*512 + h];
  }
  dst[t] = (unsigned short)f2bf(v);
}

__global__ __launch_bounds__(512, 1) void cinn_dma(
    const float* __restrict__ q, const float* __restrict__ Hg,
    const int* __restrict__ perms,
    const float* __restrict__ ls_g, const float* __restrict__ bi_g,
    const float* __restrict__ s1b1, const float* __restrict__ s1b2,
    const float* __restrict__ s2b1, const float* __restrict__ s2b2,
    const unsigned short* __restrict__ wbf,
    float* __restrict__ outz, float* __restrict__ outlj)
{
  __shared__ __align__(16) char sm[SM_SZ];
  const int tid = threadIdx.x;
  const int rowbase = blockIdx.x * 128;
  const int lane = tid & 63, wave = tid >> 6;
  const int hw = wave >> 1, ng = wave & 1;
  const int l15 = lane & 15, lq = lane >> 4;

  float* XFT = (float*)(sm + OXFT);
  short* HB  = (short*)(sm + OHB);
  float* LOGJ= (float*)(sm + OLJ);
  int*   PERM= (int*)(sm + OPERM);
  float* ELS = (float*)(sm + OELS);
  float* BIV = (float*)(sm + OBIV);
  float* SLSp= (float*)(sm + OSLS);

  // init XFT from q (coalesced read, strided LDS write, once)
  {
    int b = tid >> 2, j = tid & 3;
    const float* src = q + (size_t)(rowbase + b)*64 + j*16;
    #pragma unroll
    for (int i = 0; i < 4; ++i){
      f4v v = *(const f4v*)(src + 4*i);
      #pragma unroll
      for (int jj = 0; jj < 4; ++jj)
        XFT[(j*16 + 4*i + jj)*XFT_S + b] = v[jj];
    }
  }
  if (tid < 128) LOGJ[tid] = 0.f;
  if (tid == 0)  *SLSp = 0.f;
  __syncthreads();
  if (tid < 64){
    float p = 0.f;
    #pragma unroll
    for (int k = 0; k < 12; ++k) p += ls_g[k*64 + tid];
    atomicAdd(SLSp, p);
  }

  // H-part B-fragments: loaded ONCE, register-resident
  s8v hfr[4][4];
  #pragma unroll
  for (int nt = 0; nt < 4; ++nt){
    int b = rowbase + ng*64 + nt*16 + l15;
    #pragma unroll
    for (int kkh = 0; kkh < 4; ++kkh){
      const float* hp = Hg + (size_t)b*128 + kkh*32 + lq*8;
      f4v a = *(const f4v*)hp;
      f4v c = *(const f4v*)(hp + 4);
      u4v u = {cpk(a[0],a[1]), cpk(a[2],a[3]), cpk(c[0],c[1]), cpk(c[2],c[3])};
      hfr[nt][kkh] = __builtin_bit_cast(s8v, u);
    }
  }

  // prologue: DMA MLP0 chunk0 into buf0 (lands before first GEMM1; barriers drain vmcnt)
  {
    const unsigned short* g = wbf + wave*2560 + lane*8;      // m=0,c=0
    char* lb = sm + OW1 + wave*5120;
    #pragma unroll
    for (int k = 0; k < 5; ++k) gl_lds16(g + k*512, lb + k*1024);
  }

  for (int m = 0; m < 24; ++m){
    const int bp = m & 1;
    const unsigned short* w1sec = wbf + (size_t)m*81920;
    const unsigned short* w2sec = wbf + WF_W2 + (size_t)m*32768;
    const float* b1p = ((bp ? s1b1 : s2b1) + (m >> 1)*512);
    const float* b2p = ((bp ? s1b2 : s2b2) + (m >> 1)*64);

    if (!bp){
      int blk = m >> 1;
      if (tid < 64){
        PERM[tid] = perms[blk*64 + tid];
        ELS[tid]  = __expf(ls_g[blk*64 + tid]);
        BIV[tid]  = bi_g[blk*64 + tid];
      }
      __syncthreads();
      // permute + affine on XFT (read-all / barrier / write-all)
      {
        int d = lane, bg = wave;
        int pd = PERM[d];
        f4v v[4];
        #pragma unroll
        for (int i = 0; i < 4; ++i)
          v[i] = *(const f4v*)(XFT + pd*XFT_S + bg*16 + 4*i);
        __syncthreads();
        float e = ELS[d], bi = BIV[d];
        #pragma unroll
        for (int i = 0; i < 4; ++i){
          #pragma unroll
          for (int jj = 0; jj < 4; ++jj) v[i][jj] = fmaf(v[i][jj], e, bi);
          *(f4v*)(XFT + d*XFT_S + bg*16 + 4*i) = v[i];
        }
      }
      __syncthreads();
    }

    // x-part B-frags from XFT (dims xbase..+31)
    const int xbase = bp ? 0 : 32;
    s8v xk[4];
    #pragma unroll
    for (int nt = 0; nt < 4; ++nt){
      int b = ng*64 + nt*16 + l15;
      const float* xp = XFT + (xbase + lq*8)*XFT_S + b;
      u4v u;
      #pragma unroll
      for (int p = 0; p < 4; ++p)
        u[p] = cpk(xp[(2*p)*XFT_S], xp[(2*p+1)*XFT_S]);
      xk[nt] = __builtin_bit_cast(s8v, u);
    }

    // b2 (added by hw==0 waves at slot-write time)
    f4v b2v[4];
    if (hw == 0){
      #pragma unroll
      for (int ot = 0; ot < 4; ++ot)
        b2v[ot] = *(const f4v*)(b2p + ot*16 + lq*4);
    }

    f4v racc[4][4];
    #pragma unroll
    for (int ot = 0; ot < 4; ++ot)
      #pragma unroll
      for (int nt = 0; nt < 4; ++nt)
        racc[ot][nt] = (f4v){0.f,0.f,0.f,0.f};

    #pragma unroll
    for (int c = 0; c < 4; ++c){
      // DMA next chunk into other buffer (no regs, no LDS writes)
      if (!(m == 23 && c == 3)){
        const unsigned short* gsec = (c < 3) ? w1sec : (w1sec + 81920);
        const int cn = (c < 3) ? c + 1 : 0;
        const unsigned short* g = gsec + cn*20480 + wave*2560 + lane*8;
        char* lb = sm + OW1 + ((c+1)&1)*W1BUF + wave*5120;
        #pragma unroll
        for (int k = 0; k < 5; ++k) gl_lds16(g + k*512, lb + k*1024);
      }
      // W2 A-frags for this chunk (fragment-linear, fully coalesced 1KB/wave)
      s8v w2c[4];
      #pragma unroll
      for (int ot = 0; ot < 4; ++ot)
        w2c[ot] = *(const s8v*)(w2sec + ((c*4 + hw)*4 + ot)*512 + lane*8);
      // b1 for this chunk
      f4v b1v0 = *(const f4v*)(b1p + c*128 + hw*32 + lq*4);
      f4v b1v1 = *(const f4v*)(b1p + c*128 + hw*32 + 16 + lq*4);

      // ---- GEMM1 chunk c: A-frags at base + lane*16 (conflict-free linear)
      const short* W1c = (const short*)(sm + OW1 + (c&1)*W1BUF);
      f4v acc[2][4];
      #pragma unroll
      for (int mt = 0; mt < 2; ++mt)
        #pragma unroll
        for (int nt = 0; nt < 4; ++nt) acc[mt][nt] = (f4v){0.f,0.f,0.f,0.f};
      #pragma unroll
      for (int kk = 0; kk < 5; ++kk){
        s8v a0 = *(const s8v*)(W1c + ((hw*2 + 0)*5 + kk)*512 + lane*8);
        s8v a1 = *(const s8v*)(W1c + ((hw*2 + 1)*5 + kk)*512 + lane*8);
        #pragma unroll
        for (int nt = 0; nt < 4; ++nt){
          s8v bb = (kk == 0) ? xk[nt] : hfr[nt][kk-1];
          acc[0][nt] = MFMA16(a0, bb, acc[0][nt]);
          acc[1][nt] = MFMA16(a1, bb, acc[1][nt]);
        }
      }
      // bias + relu + pack -> own HB region (in-wave)
      #pragma unroll
      for (int mt = 0; mt < 2; ++mt){
        f4v bv = mt ? b1v1 : b1v0;
        #pragma unroll
        for (int nt = 0; nt < 4; ++nt){
          float h0 = fmaxf(acc[mt][nt][0] + bv[0], 0.f);
          float h1 = fmaxf(acc[mt][nt][1] + bv[1], 0.f);
          float h2 = fmaxf(acc[mt][nt][2] + bv[2], 0.f);
          float h3 = fmaxf(acc[mt][nt][3] + bv[3], 0.f);
          *(u2v*)(HB + (ng*64 + nt*16 + l15)*HB_S + hw*32 + mt*16 + lq*4) = (u2v){cpk(h0,h1), cpk(h2,h3)};
        }
      }
      // ---- GEMM2 k-slice: read back OWN rows (in-wave, no barrier)
      #pragma unroll
      for (int nt = 0; nt < 4; ++nt){
        s8v bb = *(const s8v*)(HB + (ng*64 + nt*16 + l15)*HB_S + hw*32 + lq*8);
        #pragma unroll
        for (int ot = 0; ot < 4; ++ot)
          racc[ot][nt] = MFMA16(w2c[ot], bb, racc[ot][nt]);
      }
      __syncthreads();   // all waves done with buf(c&1); DMA'd buf((c+1)&1) drained
    }

    // ---- reduce k-partials: bf16 slots (alias dead buf1 + HB), +b2 on hw0
    {
      short* SL = (hw < 2) ? (short*)(sm + OSLB1 + hw*SLOT_B)
                           : (short*)(sm + OHB + (hw-2)*SLOT_B);
      #pragma unroll
      for (int ot = 0; ot < 4; ++ot)
        #pragma unroll
        for (int nt = 0; nt < 4; ++nt){
          float r0 = racc[ot][nt][0], r1 = racc[ot][nt][1];
          float r2 = racc[ot][nt][2], r3 = racc[ot][nt][3];
          if (hw == 0){ r0 += b2v[ot][0]; r1 += b2v[ot][1]; r2 += b2v[ot][2]; r3 += b2v[ot][3]; }
          *(u2v*)(SL + (ng*64 + nt*16 + l15)*SL_S + ot*16 + lq*4) = (u2v){cpk(r0,r1), cpk(r2,r3)};
        }
    }
    __syncthreads();

    // ---- coupling: sum 4 slots, le = 0.636*atan(rL); y = exp(le)*x_half + rR
    {
      int b = tid & 127, og = tid >> 7;
      float le[8] = {0,0,0,0,0,0,0,0}, ra[8] = {0,0,0,0,0,0,0,0};
      #pragma unroll
      for (int ms = 0; ms < 4; ++ms){
        const short* SL = (ms < 2) ? (const short*)(sm + OSLB1 + ms*SLOT_B)
                                   : (const short*)(sm + OHB + (ms-2)*SLOT_B);
        u2v L0 = *(const u2v*)(SL + b*SL_S + og*8);
        u2v L1 = *(const u2v*)(SL + b*SL_S + og*8 + 4);
        u2v R0 = *(const u2v*)(SL + b*SL_S + 32 + og*8);
        u2v R1 = *(const u2v*)(SL + b*SL_S + 32 + og*8 + 4);
        le[0]+=bf_lo(L0[0]); le[1]+=bf_hi(L0[0]); le[2]+=bf_lo(L0[1]); le[3]+=bf_hi(L0[1]);
        le[4]+=bf_lo(L1[0]); le[5]+=bf_hi(L1[0]); le[6]+=bf_lo(L1[1]); le[7]+=bf_hi(L1[1]);
        ra[0]+=bf_lo(R0[0]); ra[1]+=bf_hi(R0[0]); ra[2]+=bf_lo(R0[1]); ra[3]+=bf_hi(R0[1]);
        ra[4]+=bf_lo(R1[0]); ra[5]+=bf_hi(R1[0]); ra[6]+=bf_lo(R1[1]); ra[7]+=bf_hi(R1[1]);
      }
      float part = 0.f;
      #pragma unroll
      for (int j = 0; j < 8; ++j){
        float l = 0.636f * atanf(le[j]);
        int d = bp*32 + og*8 + j;
        float y = __expf(l) * XFT[d*XFT_S + b] + ra[j];
        XFT[d*XFT_S + b] = y;
        part += l;
      }
      atomicAdd(&LOGJ[b], part);
    }
    __syncthreads();   // slots consumed; next MLP c=0 may DMA into buf1
  }

  // output: transpose back, coalesced global writes
  {
    int b = tid >> 2, j = tid & 3;
    float* dst = outz + (size_t)(rowbase + b)*64 + j*16;
    #pragma unroll
    for (int i = 0; i < 4; ++i){
      f4v w;
      #pragma unroll
      for (int jj = 0; jj < 4; ++jj)
        w[jj] = XFT[(j*16 + 4*i + jj)*XFT_S + b];
      *(f4v*)(dst + 4*i) = w;
    }
  }
  if (tid < 128) outlj[rowbase + tid] = LOGJ[tid] + *SLSp;
}

extern "C" void kernel_launch(void* const* d_in, const int* in_sizes, int n_in,
                              void* d_out, int out_size, void* d_ws, size_t ws_size,
                              hipStream_t stream)
{
  const float* q    = (const float*)d_in[0];
  const float* Hg   = (const float*)d_in[1];
  const int*   perms= (const int*)  d_in[2];
  const float* ls   = (const float*)d_in[3];
  const float* bi   = (const float*)d_in[4];
  const float* s1W1 = (const float*)d_in[5];
  const float* s1b1 = (const float*)d_in[6];
  const float* s1W2 = (const float*)d_in[7];
  const float* s1b2 = (const float*)d_in[8];
  const float* s2W1 = (const float*)d_in[9];
  const float* s2b1 = (const float*)d_in[10];
  const float* s2W2 = (const float*)d_in[11];
  const float* s2b2 = (const float*)d_in[12];
  float* outz  = (float*)d_out;
  float* outlj = outz + (size_t)B_ROWS * 64;

  // ws_size has accommodated the 5.25MB bf16 weight image every round
  // (round-8 FETCH breakdown confirms the bf16 branch executed)
  unsigned short* wbf = (unsigned short*)d_ws;
  cvtw_frag<<<2688, 1024, 0, stream>>>(s1W1, s1W2, s2W1, s2W2, wbf);
  cinn_dma<<<256, 512, 0, stream>>>(q, Hg, perms, ls, bi,
                                    s1b1, s1b2, s2b1, s2b2,
                                    wbf, outz, outlj);
}